// Round 3
// baseline (363.281 us; speedup 1.0000x reference)
//
#include <hip/hip_runtime.h>
#include <cstdint>
#include <cstddef>

#define HDIM 2048
#define NEXP 64
#define HC   16      // h-chunk per LDS stage
#define BTOK 64      // tokens per gemm block (1 wave)
#define PX   68      // LDS pitch (64+4)
#define PW   68
#define GATE_TOK 16  // tokens per gate block (4 waves x 4 tokens)

// ---------------------------------------------------------------------------
// Kernel 1: partial gate GEMM. 1 wave per block — no inter-wave barriers.
// grid = (N/BTOK)*hsplit, 64 threads. Wave tile 64 tok x 64 exp,
// lane tile 8 tok x 8 exp, double-buffered LDS.
// ---------------------------------------------------------------------------
__global__ __launch_bounds__(64) void moe_gemm(const float* __restrict__ x,
                                               const float* __restrict__ W,
                                               float* __restrict__ partial,
                                               int N, int HS) {
  __shared__ __align__(16) float xt[2][HC][PX];  // [buf][h][tok]
  __shared__ __align__(16) float wt[2][HC][PW];  // [buf][h][e]

  const int ntb   = N / BTOK;
  const int tb    = blockIdx.x % ntb;
  const int hsIdx = blockIdx.x / ntb;
  const int tok0  = tb * BTOK;
  const int h0    = hsIdx * HS;
  const int tid   = threadIdx.x;        // 0..63
  const int xoff  = (tid >> 3) * 8;     // 8-token group
  const int e0    = (tid & 7) * 8;      // 8-expert group
  const int srow  = tid >> 2;           // 0..15
  const int sj    = (tid & 3) * 4;      // 0,4,8,12

  float acc[8][8];
#pragma unroll
  for (int t = 0; t < 8; ++t)
#pragma unroll
    for (int e = 0; e < 8; ++e) acc[t][e] = 0.f;

  float4 xr[4], wr[4];

  // prologue: load + stage chunk 0
#pragma unroll
  for (int i = 0; i < 4; ++i) {
    xr[i] = *reinterpret_cast<const float4*>(&x[(size_t)(tok0 + srow + i * 16) * HDIM + h0 + sj]);
    wr[i] = *reinterpret_cast<const float4*>(&W[(size_t)(srow + i * 16) * HDIM + h0 + sj]);
  }
#pragma unroll
  for (int i = 0; i < 4; ++i) {
    const int r = srow + i * 16;
    xt[0][sj + 0][r] = xr[i].x; xt[0][sj + 1][r] = xr[i].y;
    xt[0][sj + 2][r] = xr[i].z; xt[0][sj + 3][r] = xr[i].w;
    wt[0][sj + 0][r] = wr[i].x; wt[0][sj + 1][r] = wr[i].y;
    wt[0][sj + 2][r] = wr[i].z; wt[0][sj + 3][r] = wr[i].w;
  }
  __syncthreads();

  const int niter = HS / HC;
  int cur = 0;
  for (int c = 0; c < niter; ++c) {
    // issue next chunk's global loads first (latency hides under the FMAs)
    if (c + 1 < niter) {
      const int hb = h0 + (c + 1) * HC;
#pragma unroll
      for (int i = 0; i < 4; ++i) {
        xr[i] = *reinterpret_cast<const float4*>(&x[(size_t)(tok0 + srow + i * 16) * HDIM + hb + sj]);
        wr[i] = *reinterpret_cast<const float4*>(&W[(size_t)(srow + i * 16) * HDIM + hb + sj]);
      }
    }
    // compute current buffer
#pragma unroll
    for (int h = 0; h < HC; ++h) {
      const float4 a0 = *reinterpret_cast<const float4*>(&xt[cur][h][xoff]);
      const float4 a1 = *reinterpret_cast<const float4*>(&xt[cur][h][xoff + 4]);
      const float4 b0 = *reinterpret_cast<const float4*>(&wt[cur][h][e0]);
      const float4 b1 = *reinterpret_cast<const float4*>(&wt[cur][h][e0 + 4]);
      const float xs[8] = {a0.x, a0.y, a0.z, a0.w, a1.x, a1.y, a1.z, a1.w};
      const float wv[8] = {b0.x, b0.y, b0.z, b0.w, b1.x, b1.y, b1.z, b1.w};
#pragma unroll
      for (int t = 0; t < 8; ++t)
#pragma unroll
        for (int e = 0; e < 8; ++e)
          acc[t][e] = fmaf(xs[t], wv[e], acc[t][e]);
    }
    // stage next chunk into the other buffer
    if (c + 1 < niter) {
      const int nx = cur ^ 1;
#pragma unroll
      for (int i = 0; i < 4; ++i) {
        const int r = srow + i * 16;
        xt[nx][sj + 0][r] = xr[i].x; xt[nx][sj + 1][r] = xr[i].y;
        xt[nx][sj + 2][r] = xr[i].z; xt[nx][sj + 3][r] = xr[i].w;
        wt[nx][sj + 0][r] = wr[i].x; wt[nx][sj + 1][r] = wr[i].y;
        wt[nx][sj + 2][r] = wr[i].z; wt[nx][sj + 3][r] = wr[i].w;
      }
    }
    __syncthreads();   // 1-wave block: just waitcnt + free barrier
    cur ^= 1;
  }

  // write partial logits: partial[hs][tok][e]
  const size_t base = ((size_t)hsIdx * N + (tok0 + xoff)) * NEXP + e0;
#pragma unroll
  for (int t = 0; t < 8; ++t) {
    *reinterpret_cast<float4*>(&partial[base + (size_t)t * NEXP]) =
        make_float4(acc[t][0], acc[t][1], acc[t][2], acc[t][3]);
    *reinterpret_cast<float4*>(&partial[base + (size_t)t * NEXP + 4]) =
        make_float4(acc[t][4], acc[t][5], acc[t][6], acc[t][7]);
  }
}

// ---------------------------------------------------------------------------
// Kernel 2: reduce H-splits, softmax, top-2, renorm, loss partials; the LAST
// block (device counter) reduces per-block partials and writes the loss.
// grid = N/GATE_TOK blocks, 256 threads (4 waves x 4 tokens each).
// ---------------------------------------------------------------------------
template <int HSPLIT>
__global__ __launch_bounds__(256) void moe_gate(const float* __restrict__ partial,
                                                int N, int GB,
                                                float* __restrict__ outS,
                                                float* __restrict__ outI,
                                                float* __restrict__ esumP,
                                                float* __restrict__ lse2P,
                                                unsigned* __restrict__ counter,
                                                float* __restrict__ outL) {
  __shared__ float es[4][NEXP];
  __shared__ float l2[4];
  __shared__ float esF[NEXP];
  __shared__ float l2F[4];
  __shared__ int lastFlag;
  const int tid  = threadIdx.x;
  const int lane = tid & 63;
  const int w    = tid >> 6;
  const int base = blockIdx.x * GATE_TOK + w * 4;

  // all partial loads up front (independent -> deep MLP)
  float v[4][HSPLIT];
#pragma unroll
  for (int tt = 0; tt < 4; ++tt)
#pragma unroll
    for (int hs = 0; hs < HSPLIT; ++hs)
      v[tt][hs] = partial[((size_t)hs * N + base + tt) * NEXP + lane];

  float logit[4];
#pragma unroll
  for (int tt = 0; tt < 4; ++tt) {
    float s = v[tt][0];
#pragma unroll
    for (int hs = 1; hs < HSPLIT; ++hs) s += v[tt][hs];  // ascending hs order
    logit[tt] = s;
  }

  // interleaved wave softmax over 64 experts (4 tokens in flight)
  float m[4], p[4], s[4], sc[4];
#pragma unroll
  for (int tt = 0; tt < 4; ++tt) m[tt] = logit[tt];
#pragma unroll
  for (int d = 1; d < 64; d <<= 1)
#pragma unroll
    for (int tt = 0; tt < 4; ++tt) m[tt] = fmaxf(m[tt], __shfl_xor(m[tt], d));
#pragma unroll
  for (int tt = 0; tt < 4; ++tt) { p[tt] = expf(logit[tt] - m[tt]); s[tt] = p[tt]; }
#pragma unroll
  for (int d = 1; d < 64; d <<= 1)
#pragma unroll
    for (int tt = 0; tt < 4; ++tt) s[tt] += __shfl_xor(s[tt], d);
#pragma unroll
  for (int tt = 0; tt < 4; ++tt) sc[tt] = p[tt] / s[tt];

  // top-1 (ties -> lower index), 4 tokens interleaved
  float v1[4]; int i1[4];
#pragma unroll
  for (int tt = 0; tt < 4; ++tt) { v1[tt] = sc[tt]; i1[tt] = lane; }
#pragma unroll
  for (int d = 1; d < 64; d <<= 1)
#pragma unroll
    for (int tt = 0; tt < 4; ++tt) {
      const float pv = __shfl_xor(v1[tt], d);
      const int   pi = __shfl_xor(i1[tt], d);
      if (pv > v1[tt] || (pv == v1[tt] && pi < i1[tt])) { v1[tt] = pv; i1[tt] = pi; }
    }
  // top-2 excluding i1 (scores >= 0)
  float v2[4]; int i2[4];
#pragma unroll
  for (int tt = 0; tt < 4; ++tt) { v2[tt] = (lane == i1[tt]) ? -1.f : sc[tt]; i2[tt] = lane; }
#pragma unroll
  for (int d = 1; d < 64; d <<= 1)
#pragma unroll
    for (int tt = 0; tt < 4; ++tt) {
      const float pv = __shfl_xor(v2[tt], d);
      const int   pi = __shfl_xor(i2[tt], d);
      if (pv > v2[tt] || (pv == v2[tt] && pi < i2[tt])) { v2[tt] = pv; i2[tt] = pi; }
    }

  if (lane == 0) {
#pragma unroll
    for (int tt = 0; tt < 4; ++tt) {
      const int t = base + tt;
      const float mx  = fmaxf(v1[tt], v2[tt]);
      const float e1  = expf(v1[tt] - mx), e2 = expf(v2[tt] - mx);
      const float inv = 1.f / (e1 + e2);
      *reinterpret_cast<float2*>(&outS[2 * (size_t)t]) = make_float2(e1 * inv, e2 * inv);
      *reinterpret_cast<float2*>(&outI[2 * (size_t)t]) = make_float2((float)i1[tt], (float)i2[tt]);
    }
  }

  // loss partials: per-lane expert-score sum, per-wave lse^2 sum
  const float esum = ((sc[0] + sc[1]) + sc[2]) + sc[3];
  float lse2 = 0.f;
#pragma unroll
  for (int tt = 0; tt < 4; ++tt) {
    const float lse = m[tt] + logf(s[tt]);   // identical in all lanes
    lse2 += lse * lse;
  }
  es[w][lane] = esum;
  if (lane == 0) l2[w] = lse2;
  __syncthreads();
  if (tid < NEXP)
    esumP[(size_t)tid * GB + blockIdx.x] = es[0][tid] + es[1][tid] + es[2][tid] + es[3][tid];
  if (tid == 0)
    lse2P[blockIdx.x] = l2[0] + l2[1] + l2[2] + l2[3];

  // ---- last block reduces all per-block partials (deterministic order) ----
  __threadfence();
  if (tid == 0) lastFlag = (atomicAdd(counter, 1u) == (unsigned)(GB - 1));
  __syncthreads();
  if (!lastFlag) return;
  __threadfence();

  // expert sums: thread (e = tid>>2, q = tid&3) reads GB/4 contiguous floats
  const int e = tid >> 2, q = tid & 3;
  const int seg = GB / 4;
  const float4* colp = reinterpret_cast<const float4*>(&esumP[(size_t)e * GB + q * seg]);
  float a = 0.f;
  for (int i = 0; i < seg / 4; ++i) {
    const float4 t4 = colp[i];
    a += ((t4.x + t4.y) + t4.z) + t4.w;
  }
  a += __shfl_xor(a, 1);
  a += __shfl_xor(a, 2);
  if (q == 0) esF[e] = a;

  // lse^2 total: 256 threads x float4 over GB entries
  float la = 0.f;
  for (int i = tid; i * 4 < GB; i += 256) {
    const float4 t4 = reinterpret_cast<const float4*>(lse2P)[i];
    la += ((t4.x + t4.y) + t4.z) + t4.w;
  }
#pragma unroll
  for (int d = 1; d < 64; d <<= 1) la += __shfl_xor(la, d);
  if (lane == 0) l2F[w] = la;
  __syncthreads();

  if (tid < NEXP) {
    const float load = esF[tid] / (float)N;
    const float dv   = load - 1.0f / 64.0f;
    float qq = dv * dv;
#pragma unroll
    for (int d = 1; d < 64; d <<= 1) qq += __shfl_xor(qq, d);
    if (tid == 0) {
      const float lseSum = ((l2F[0] + l2F[1]) + l2F[2]) + l2F[3];
      outL[0] = 0.01f * qq + 1e-4f * (lseSum / (float)N);
    }
  }
}

// ---------------------------------------------------------------------------
extern "C" void kernel_launch(void* const* d_in, const int* in_sizes, int n_in,
                              void* d_out, int out_size, void* d_ws, size_t ws_size,
                              hipStream_t stream) {
  const float* x = (const float*)d_in[0];
  const float* W = (const float*)d_in[1];
  const int N  = in_sizes[0] / HDIM;   // 16384
  const int GB = N / GATE_TOK;         // 1024

  float* out  = (float*)d_out;
  float* outS = out;                   // [N,2]
  float* outI = out + (size_t)2 * N;   // [N,2]
  float* outL = out + (size_t)4 * N;   // scalar

  // largest H-split the workspace can hold
  int hsplit = 1;
  for (int h = 8; h >= 1; h >>= 1) {
    const size_t need = (size_t)h * N * NEXP * sizeof(float)
                      + (size_t)NEXP * GB * sizeof(float)
                      + (size_t)GB * sizeof(float) + 256;
    if (ws_size >= need) { hsplit = h; break; }
  }
  const int HS = HDIM / hsplit;

  float*    partial = (float*)d_ws;                                            // [hsplit][N][64]
  float*    esumP   = (float*)((char*)d_ws + (size_t)hsplit * N * NEXP * 4);   // [64][GB]
  float*    lse2P   = esumP + (size_t)NEXP * GB;                               // [GB]
  unsigned* counter = (unsigned*)(lse2P + GB);

  hipMemsetAsync(counter, 0, sizeof(unsigned), stream);

  const int ntb = N / BTOK;
  moe_gemm<<<dim3(ntb * hsplit), dim3(64), 0, stream>>>(x, W, partial, N, HS);
  switch (hsplit) {
    case 8: moe_gate<8><<<dim3(GB), dim3(256), 0, stream>>>(partial, N, GB, outS, outI, esumP, lse2P, counter, outL); break;
    case 4: moe_gate<4><<<dim3(GB), dim3(256), 0, stream>>>(partial, N, GB, outS, outI, esumP, lse2P, counter, outL); break;
    case 2: moe_gate<2><<<dim3(GB), dim3(256), 0, stream>>>(partial, N, GB, outS, outI, esumP, lse2P, counter, outL); break;
    default: moe_gate<1><<<dim3(GB), dim3(256), 0, stream>>>(partial, N, GB, outS, outI, esumP, lse2P, counter, outL); break;
  }
}

// Round 4
// 255.971 us; speedup vs baseline: 1.4192x; 1.4192x over previous
//
#include <hip/hip_runtime.h>
#include <cmath>
#include <cstdint>
#include <cstddef>

#define HDIM  2048
#define HHALF 1024
#define HC    16                 // h-cols staged per chunk per half
#define NCHUNK (HHALF / HC)      // 64
#define NEXP  64
#define BTOK  64                 // tokens per block
#define PL    68                 // padded leading dim for LDS tiles

// ---------------------------------------------------------------------------
// Fused kernel: gate GEMM (full H, block-internal split) + softmax + top-2 +
// renorm + per-block loss partials. grid = N/64 blocks x 256 threads.
// Wave w = (eh = w&1, hh = w>>1): 64 tok x 32 exp x 1024 h. No atomics/fences.
// ---------------------------------------------------------------------------
__global__ __launch_bounds__(256) void moe_fused(const float* __restrict__ x,
                                                 const float* __restrict__ W,
                                                 float* __restrict__ outS,
                                                 float* __restrict__ outI,
                                                 float* __restrict__ esumP,
                                                 float* __restrict__ lse2P,
                                                 int N) {
  __shared__ __align__(16) float xt[2][2][HC][PL];  // [buf][hh][c][tok]
  __shared__ __align__(16) float wt[2][2][HC][PL];  // [buf][hh][c][e]
  __shared__ __align__(16) float lg[BTOK][PL];      // logits, later p-values
  __shared__ float invS[BTOK];
  __shared__ float lseL[BTOK];
  __shared__ float esL[4][NEXP];

  const int b    = blockIdx.x;
  const int tok0 = b * BTOK;
  const int tid  = threadIdx.x;
  const int lane = tid & 63;
  const int w    = tid >> 6;
  const int eh   = w & 1;
  const int hh   = w >> 1;
  const int tg   = lane >> 3;          // token group 0..7 (8 tokens each)
  const int eg   = lane & 7;           // expert group 0..7 (4 experts each)
  const int row  = tid >> 2;           // staging row 0..63
  const int cq   = tid & 3;            // staging col quad 0..3

  const float* xp = x + (size_t)(tok0 + row) * HDIM + cq * 4;
  const float* wp = W + (size_t)row * HDIM + cq * 4;

  float acc[8][4];
#pragma unroll
  for (int t = 0; t < 8; ++t)
#pragma unroll
    for (int e = 0; e < 4; ++e) acc[t][e] = 0.f;

  // ---- prologue: stage chunk 0 ----
  {
    const float4 x0 = *reinterpret_cast<const float4*>(xp);
    const float4 x1 = *reinterpret_cast<const float4*>(xp + HHALF);
    const float4 w0 = *reinterpret_cast<const float4*>(wp);
    const float4 w1 = *reinterpret_cast<const float4*>(wp + HHALF);
    const int cc = cq * 4;
    xt[0][0][cc+0][row] = x0.x; xt[0][0][cc+1][row] = x0.y;
    xt[0][0][cc+2][row] = x0.z; xt[0][0][cc+3][row] = x0.w;
    xt[0][1][cc+0][row] = x1.x; xt[0][1][cc+1][row] = x1.y;
    xt[0][1][cc+2][row] = x1.z; xt[0][1][cc+3][row] = x1.w;
    wt[0][0][cc+0][row] = w0.x; wt[0][0][cc+1][row] = w0.y;
    wt[0][0][cc+2][row] = w0.z; wt[0][0][cc+3][row] = w0.w;
    wt[0][1][cc+0][row] = w1.x; wt[0][1][cc+1][row] = w1.y;
    wt[0][1][cc+2][row] = w1.z; wt[0][1][cc+3][row] = w1.w;
  }
  __syncthreads();

  const int trow = tg * 8;
  const int ecol = (eh << 5) + (eg << 2);

  int cur = 0;
  for (int c = 0; c < NCHUNK; ++c) {
    float4 x0, x1, w0, w1;
    const bool more = (c + 1 < NCHUNK);
    if (more) {  // issue next chunk's loads before compute
      const int off = (c + 1) * HC;
      x0 = *reinterpret_cast<const float4*>(xp + off);
      x1 = *reinterpret_cast<const float4*>(xp + HHALF + off);
      w0 = *reinterpret_cast<const float4*>(wp + off);
      w1 = *reinterpret_cast<const float4*>(wp + HHALF + off);
    }
#pragma unroll
    for (int h = 0; h < HC; ++h) {
      const float4 a0 = *reinterpret_cast<const float4*>(&xt[cur][hh][h][trow]);
      const float4 a1 = *reinterpret_cast<const float4*>(&xt[cur][hh][h][trow + 4]);
      const float4 bv = *reinterpret_cast<const float4*>(&wt[cur][hh][h][ecol]);
      const float xs[8] = {a0.x, a0.y, a0.z, a0.w, a1.x, a1.y, a1.z, a1.w};
      const float wv[4] = {bv.x, bv.y, bv.z, bv.w};
#pragma unroll
      for (int t = 0; t < 8; ++t)
#pragma unroll
        for (int e = 0; e < 4; ++e)
          acc[t][e] = fmaf(xs[t], wv[e], acc[t][e]);
    }
    if (more) {
      const int nb = cur ^ 1, cc = cq * 4;
      xt[nb][0][cc+0][row] = x0.x; xt[nb][0][cc+1][row] = x0.y;
      xt[nb][0][cc+2][row] = x0.z; xt[nb][0][cc+3][row] = x0.w;
      xt[nb][1][cc+0][row] = x1.x; xt[nb][1][cc+1][row] = x1.y;
      xt[nb][1][cc+2][row] = x1.z; xt[nb][1][cc+3][row] = x1.w;
      wt[nb][0][cc+0][row] = w0.x; wt[nb][0][cc+1][row] = w0.y;
      wt[nb][0][cc+2][row] = w0.z; wt[nb][0][cc+3][row] = w0.w;
      wt[nb][1][cc+0][row] = w1.x; wt[nb][1][cc+1][row] = w1.y;
      wt[nb][1][cc+2][row] = w1.z; wt[nb][1][cc+3][row] = w1.w;
    }
    __syncthreads();
    cur ^= 1;
  }

  // ---- merge the two h-halves into lg (fixed order: hh0 then hh1) ----
  if (hh == 0) {
#pragma unroll
    for (int t = 0; t < 8; ++t)
      *reinterpret_cast<float4*>(&lg[trow + t][ecol]) =
          make_float4(acc[t][0], acc[t][1], acc[t][2], acc[t][3]);
  }
  __syncthreads();
  if (hh == 1) {
#pragma unroll
    for (int t = 0; t < 8; ++t) {
      float4 cv = *reinterpret_cast<const float4*>(&lg[trow + t][ecol]);
      cv.x += acc[t][0]; cv.y += acc[t][1]; cv.z += acc[t][2]; cv.w += acc[t][3];
      *reinterpret_cast<float4*>(&lg[trow + t][ecol]) = cv;
    }
  }
  __syncthreads();

  // ---- gate: lane-per-token serial scan (16 active lanes per wave) ----
  if (lane < 16) {
    const int t = w * 16 + lane;
    // pass 1: online top-2 over logits (monotone with scores); jax tie rules
    float m = -INFINITY, v2 = -INFINITY;
    int i1 = 0, i2 = 0;
#pragma unroll
    for (int e4 = 0; e4 < 16; ++e4) {
      const float4 lv = *reinterpret_cast<const float4*>(&lg[t][e4 * 4]);
      const float ls[4] = {lv.x, lv.y, lv.z, lv.w};
#pragma unroll
      for (int j = 0; j < 4; ++j) {
        const float l = ls[j];
        const int e = e4 * 4 + j;
        if (l > m)       { v2 = m; i2 = i1; m = l; i1 = e; }
        else if (l > v2) { v2 = l; i2 = e; }
      }
    }
    // pass 2: exp-sum (ascending e), store p back into lg row
    float s = 0.f;
#pragma unroll
    for (int e4 = 0; e4 < 16; ++e4) {
      float4 lv = *reinterpret_cast<const float4*>(&lg[t][e4 * 4]);
      lv.x = expf(lv.x - m); s += lv.x;
      lv.y = expf(lv.y - m); s += lv.y;
      lv.z = expf(lv.z - m); s += lv.z;
      lv.w = expf(lv.w - m); s += lv.w;
      *reinterpret_cast<float4*>(&lg[t][e4 * 4]) = lv;
    }
    const float v1s = 1.f / s;                 // score of top-1
    const float v2s = expf(v2 - m) / s;        // score of top-2
    const float mx  = fmaxf(v1s, v2s);
    const float e1  = expf(v1s - mx), e2 = expf(v2s - mx);
    const float inv = 1.f / (e1 + e2);
    *reinterpret_cast<float2*>(&outS[2 * (size_t)(tok0 + t)]) = make_float2(e1 * inv, e2 * inv);
    *reinterpret_cast<float2*>(&outI[2 * (size_t)(tok0 + t)]) = make_float2((float)i1, (float)i2);
    invS[t] = v1s;
    const float lse = m + logf(s);
    lseL[t] = lse * lse;
  }
  __syncthreads();

  // ---- loss partials: expert-major score sums (lane = expert) ----
  float ea = 0.f;
#pragma unroll
  for (int i = 0; i < 16; ++i) {
    const int t = w * 16 + i;                  // ascending t within wave
    ea = fmaf(lg[t][lane], invS[t], ea);
  }
  esL[w][lane] = ea;
  __syncthreads();
  if (w == 0) {
    const float tot = ((esL[0][lane] + esL[1][lane]) + esL[2][lane]) + esL[3][lane];
    esumP[(size_t)b * NEXP + lane] = tot;
  }
  if (w == 1) {
    float la = lseL[lane];
#pragma unroll
    for (int d = 1; d < 64; d <<= 1) la += __shfl_xor(la, d);
    if (lane == 0) lse2P[b] = la;
  }
}

// ---------------------------------------------------------------------------
// Loss finalize: 1 block, 256 threads. Deterministic fixed-order reduction.
// ---------------------------------------------------------------------------
__global__ __launch_bounds__(256) void moe_loss(const float* __restrict__ esumP,
                                                const float* __restrict__ lse2P,
                                                float* __restrict__ outL,
                                                int N, int NB) {
  __shared__ float es4[4][NEXP];
  __shared__ float l4[4];
  const int tid = threadIdx.x, lane = tid & 63, w = tid >> 6;

  const int seg = NB / 4;
  float a = 0.f;
  for (int i = 0; i < seg; ++i)
    a += esumP[(size_t)(w * seg + i) * NEXP + lane];
  es4[w][lane] = a;

  float la = 0.f;
  for (int i = tid; i < NB; i += 256) la += lse2P[i];
#pragma unroll
  for (int d = 1; d < 64; d <<= 1) la += __shfl_xor(la, d);
  if (lane == 0) l4[w] = la;
  __syncthreads();

  if (tid < NEXP) {
    const float tot  = ((es4[0][tid] + es4[1][tid]) + es4[2][tid]) + es4[3][tid];
    const float load = tot / (float)N;
    const float dv   = load - 1.0f / 64.0f;
    float q = dv * dv;
#pragma unroll
    for (int d = 1; d < 64; d <<= 1) q += __shfl_xor(q, d);
    if (tid == 0) {
      const float lseSum = ((l4[0] + l4[1]) + l4[2]) + l4[3];
      outL[0] = 0.01f * q + 1e-4f * (lseSum / (float)N);
    }
  }
}

// ---------------------------------------------------------------------------
extern "C" void kernel_launch(void* const* d_in, const int* in_sizes, int n_in,
                              void* d_out, int out_size, void* d_ws, size_t ws_size,
                              hipStream_t stream) {
  const float* x = (const float*)d_in[0];
  const float* W = (const float*)d_in[1];
  const int N  = in_sizes[0] / HDIM;   // 16384
  const int NB = N / BTOK;             // 256

  float* out  = (float*)d_out;
  float* outS = out;                   // [N,2]
  float* outI = out + (size_t)2 * N;   // [N,2]
  float* outL = out + (size_t)4 * N;   // scalar

  float* esumP = (float*)d_ws;                 // [NB][64]
  float* lse2P = esumP + (size_t)NB * NEXP;    // [NB]

  moe_fused<<<dim3(NB), dim3(256), 0, stream>>>(x, W, outS, outI, esumP, lse2P, N);
  moe_loss<<<dim3(1), dim3(256), 0, stream>>>(esumP, lse2P, outL, N, NB);
}